// Round 1
// baseline (735.351 us; speedup 1.0000x reference)
//
#include <hip/hip_runtime.h>
#include <hip/hip_cooperative_groups.h>
#include <math.h>

namespace cg = cooperative_groups;

// SimilarityTreeLSTM on MI355X — round 3: single persistent cooperative kernel.
//
// Round-2 analysis: 16 stream-ordered kernel launches, each <60us, total 397us
// vs ~20us of actual HW work (6 GFLOP + 35MB). Launch/serialization-bound.
// This round: ONE cooperative kernel, 256 blocks x 256 threads (>=1 block/CU,
// co-residency guaranteed), dependencies expressed as grid.sync() (12 total).
//
// Structural changes vs round 2:
//  * phase0 (leaves, j in [0,171) per tree): children are all the pad zero
//    row, so iou = xiou + b_iouh exactly (MFMA acc was exactly 0) and the
//    f-gate contributes f*0 = 0. GEMM stage deleted; specialized leaf gating.
//  * final phase (roots, B=1) gating + head1 + head2 fused into block 0
//    (1024x512 head GEMV done by one block; removes hid_raw atomics + 2 syncs).
//
// Level decomposition (deterministic from _build_children(512,4), j = 511-i):
//   leaves [0,171) | ph d4 [171,427) | d3 [427,491) | d2 [491,507)
//   | d1 [507,511) | root [511,512)
// Children of a depth-d node are all at depth d+1 (the previous phase).
// Pad child index 512 maps to a per-tree zero row ([2][513][512] state bufs).
//
// MFMA: v_mfma_f32_16x16x32_bf16. A-frag: lane holds A[m=lane&15][k=q*8+j],
// B-frag: B[k=q*8+j][n=lane&15] (W stored transposed -> 16B contiguous load),
// C/D: col=lane&15, row=q*4+reg.  [per guide §3, verified]

typedef __attribute__((ext_vector_type(8))) __bf16 bf16x8;
typedef __attribute__((ext_vector_type(4))) float f32x4;

#define GRID 256

__device__ __forceinline__ float sigm(float x) { return 1.0f / (1.0f + __expf(-x)); }

__device__ __forceinline__ unsigned short f2bf(float f) {
    union { float f; unsigned int u; } v; v.f = f;
    unsigned int r = v.u + 0x7FFF + ((v.u >> 16) & 1);
    return (unsigned short)(r >> 16);
}
__device__ __forceinline__ float bf2f(unsigned short b) {
    union { unsigned int u; float f; } v; v.u = ((unsigned int)b) << 16;
    return v.f;
}
__device__ __forceinline__ f32x4 mfma16(bf16x8 a, bf16x8 b, f32x4 c) {
    return __builtin_amdgcn_mfma_f32_16x16x32_bf16(a, b, c, 0, 0, 0);
}
__device__ __forceinline__ bf16x8 load_f32_as_bf8(const float* p) {
    float4 x = *(const float4*)p;
    float4 y = *(const float4*)(p + 4);
    bf16x8 r;
    r[0] = (__bf16)x.x; r[1] = (__bf16)x.y; r[2] = (__bf16)x.z; r[3] = (__bf16)x.w;
    r[4] = (__bf16)y.x; r[5] = (__bf16)y.y; r[6] = (__bf16)y.z; r[7] = (__bf16)y.w;
    return r;
}

struct Args {
    const int   *lin, *rin, *lch, *rch;
    const float *emb;
    const float *W_ioux, *b_ioux, *W_iouh, *b_iouh;
    const float *W_fx, *b_fx, *W_fh, *b_fh;
    const float *Wh, *bh, *Wp, *bp;
    unsigned short *WiouhT, *WfhT, *WxT, *Whb, *xcat, *hbf;
    float *cbuf, *ioub, *fpre, *out;
};

// 32x32 fp32->bf16 transpose tile via LDS
__device__ __forceinline__
void ttile(const float* __restrict__ src, int lds_, unsigned short* __restrict__ dst,
           int ldd, int k0, int n0, float (*ts)[33], int tid)
{
    const int tx = tid & 31, ty = tid >> 5;
#pragma unroll
    for (int i = 0; i < 4; ++i)
        ts[ty + 8 * i][tx] = src[(size_t)(k0 + ty + 8 * i) * lds_ + n0 + tx];
    __syncthreads();
#pragma unroll
    for (int i = 0; i < 4; ++i)
        dst[(size_t)(n0 + ty + 8 * i) * ldd + k0 + tx] = f2bf(ts[tx][ty + 8 * i]);
}

// -------- per-phase fused gather + dual GEMM (one block-task) --------------
__device__ __forceinline__
void gemm_task(int t, int lo, int B, int mti1, int nti1, int mti2, const Args& a)
{
    const int B2 = 2 * B;
    const int tid = threadIdx.x, w = tid >> 6, lane = tid & 63;
    const int m = lane & 15, q = lane >> 4;

    if (t < nti1) {
        // iou: [B2,512] (child-h sum, gathered on the fly) x [512,1536]
        const int mt = t % mti1, nb = t / mti1;
        const int colbase = nb * 256 + w * 64;
        const unsigned short* pA[2][4];
#pragma unroll
        for (int i = 0; i < 2; ++i) {
            const int r = mt * 32 + m + i * 16;
            int c[4] = {512, 512, 512, 512};
            int tree = 0;
            if (r < B2) {
                tree = (r >= B) ? 1 : 0;
                const int j = lo + r - tree * B;
                const int* ch = (tree ? a.rch : a.lch) + 4 * j;
                c[0] = ch[0]; c[1] = ch[1]; c[2] = ch[2]; c[3] = ch[3];
            }
            const unsigned short* hb = a.hbf + (size_t)tree * 513 * 512;
#pragma unroll
            for (int s = 0; s < 4; ++s) pA[i][s] = hb + (size_t)c[s] * 512;
        }
        f32x4 acc[2][4];
#pragma unroll
        for (int i = 0; i < 2; ++i)
#pragma unroll
            for (int j = 0; j < 4; ++j) acc[i][j] = (f32x4){0.f, 0.f, 0.f, 0.f};

        for (int k0 = 0; k0 < 512; k0 += 32) {
            const int koff = k0 + q * 8;
            bf16x8 af[2];
#pragma unroll
            for (int i = 0; i < 2; ++i) {
                float s[8] = {0.f, 0.f, 0.f, 0.f, 0.f, 0.f, 0.f, 0.f};
#pragma unroll
                for (int cc = 0; cc < 4; ++cc) {
                    bf16x8 v = *(const bf16x8*)(pA[i][cc] + koff);
#pragma unroll
                    for (int j = 0; j < 8; ++j) s[j] += (float)v[j];
                }
                bf16x8 av;
#pragma unroll
                for (int j = 0; j < 8; ++j) av[j] = (__bf16)s[j];
                af[i] = av;
            }
#pragma unroll
            for (int jj = 0; jj < 4; ++jj) {
                bf16x8 b = *(const bf16x8*)(a.WiouhT + (size_t)(colbase + jj * 16 + m) * 512 + koff);
                acc[0][jj] = mfma16(af[0], b, acc[0][jj]);
                acc[1][jj] = mfma16(af[1], b, acc[1][jj]);
            }
        }
#pragma unroll
        for (int i = 0; i < 2; ++i)
#pragma unroll
            for (int jj = 0; jj < 4; ++jj)
#pragma unroll
                for (int rr = 0; rr < 4; ++rr) {
                    const int R = mt * 32 + i * 16 + q * 4 + rr;
                    if (R < B2) {
                        const int tr = (R >= B) ? 1 : 0;
                        const int jR = lo + R - tr * B;
                        const int col = colbase + jj * 16 + m;
                        a.ioub[(size_t)R * 1536 + col] = acc[i][jj][rr] + a.b_iouh[col]
                            + bf2f(a.xcat[(size_t)(tr * 512 + jR) * 2048 + col]);
                    }
                }
    } else {
        // f: [4*B2,512] (child h rows, direct) x [512,512]
        t -= nti1;
        const int mt = t % mti2, nb = t / mti2;
        const int colbase = nb * 256 + w * 64;
        const unsigned short* pA[2];
#pragma unroll
        for (int i = 0; i < 2; ++i) {
            const int rf = mt * 32 + m + i * 16;
            int tree = 0, c = 512;
            if (rf < 4 * B2) {
                const int r = rf >> 2, s = rf & 3;
                tree = (r >= B) ? 1 : 0;
                const int j = lo + r - tree * B;
                c = ((tree ? a.rch : a.lch) + 4 * j)[s];
            }
            pA[i] = a.hbf + ((size_t)tree * 513 + c) * 512;
        }
        f32x4 acc[2][4];
#pragma unroll
        for (int i = 0; i < 2; ++i)
#pragma unroll
            for (int j = 0; j < 4; ++j) acc[i][j] = (f32x4){0.f, 0.f, 0.f, 0.f};

        for (int k0 = 0; k0 < 512; k0 += 32) {
            const int koff = k0 + q * 8;
            bf16x8 a0 = *(const bf16x8*)(pA[0] + koff);
            bf16x8 a1 = *(const bf16x8*)(pA[1] + koff);
#pragma unroll
            for (int jj = 0; jj < 4; ++jj) {
                bf16x8 b = *(const bf16x8*)(a.WfhT + (size_t)(colbase + jj * 16 + m) * 512 + koff);
                acc[0][jj] = mfma16(a0, b, acc[0][jj]);
                acc[1][jj] = mfma16(a1, b, acc[1][jj]);
            }
        }
#pragma unroll
        for (int i = 0; i < 2; ++i)
#pragma unroll
            for (int jj = 0; jj < 4; ++jj)
#pragma unroll
                for (int rr = 0; rr < 4; ++rr) {
                    const int R = mt * 32 + i * 16 + q * 4 + rr;
                    if (R < 4 * B2) {
                        const int rR = R >> 2;
                        const int tr = (rR >= B) ? 1 : 0;
                        const int jR = lo + rR - tr * B;
                        const int col = colbase + jj * 16 + m;
                        a.fpre[(size_t)R * 512 + col] = acc[i][jj][rr] + a.b_fh[col]
                            + bf2f(a.xcat[(size_t)(tr * 512 + jR) * 2048 + 1536 + col]);
                    }
                }
    }
}

// -------- general gating for one node row (writes c fp32, h bf16) ----------
__device__ __forceinline__
void gate_row(int r, int lo, int B, const Args& a)
{
    const int tid = threadIdx.x;
    const int tree = (r >= B) ? 1 : 0;
    const int j = lo + r - tree * B;
    const int* ch = (tree ? a.rch : a.lch) + 4 * j;
    const int c0 = ch[0], c1 = ch[1], c2 = ch[2], c3 = ch[3];
    float* cb = a.cbuf + (size_t)tree * 513 * 512;
    unsigned short* hb = a.hbf + (size_t)tree * 513 * 512;
    const float* ir = a.ioub + (size_t)r * 1536;
    const float* fr = a.fpre + (size_t)r * 4 * 512;
#pragma unroll
    for (int u = 0; u < 2; ++u) {
        const int col = tid + u * 256;
        const float ig = sigm(ir[col]);
        const float og = sigm(ir[512 + col]);
        const float ug = tanhf(ir[1024 + col]);
        float cv = ig * ug
            + sigm(fr[col])        * cb[(size_t)c0 * 512 + col]
            + sigm(fr[512 + col])  * cb[(size_t)c1 * 512 + col]
            + sigm(fr[1024 + col]) * cb[(size_t)c2 * 512 + col]
            + sigm(fr[1536 + col]) * cb[(size_t)c3 * 512 + col];
        cb[(size_t)j * 512 + col] = cv;
        hb[(size_t)j * 512 + col] = f2bf(og * tanhf(cv));
    }
}

// ---------------------------- the mega-kernel ------------------------------
__global__ __launch_bounds__(256, 1)
void mega(Args a)
{
    cg::grid_group grid = cg::this_grid();
    const int tid = threadIdx.x, bid = blockIdx.x;
    const int G = gridDim.x;
    __shared__ float ts[32][33];

    // ---- stage A: weight transpose/convert + zero pad rows (2305 tasks) ----
    for (int t = bid; t < 2305; t += G) {
        if (t < 768) {                       // W_iouh [512][1536] -> WiouhT
            ttile(a.W_iouh, 1536, a.WiouhT, 512, (t & 15) * 32, (t >> 4) * 32, ts, tid);
        } else if (t < 1024) {               // W_fh -> WfhT
            const int tt = t - 768;
            ttile(a.W_fh, 512, a.WfhT, 512, (tt & 15) * 32, (tt >> 4) * 32, ts, tid);
        } else if (t < 1792) {               // W_ioux -> WxT rows [0,1536)
            const int tt = t - 1024;
            ttile(a.W_ioux, 1536, a.WxT, 512, (tt & 15) * 32, (tt >> 4) * 32, ts, tid);
        } else if (t < 2048) {               // W_fx -> WxT rows [1536,2048)
            const int tt = t - 1792;
            ttile(a.W_fx, 512, a.WxT + (size_t)1536 * 512, 512, (tt & 15) * 32, (tt >> 4) * 32, ts, tid);
        } else if (t < 2304) {               // Wh -> bf16 copy
            size_t base = (size_t)(t - 2048) * 2048 + tid;
#pragma unroll
            for (int i = 0; i < 8; ++i) a.Whb[base + 256 * i] = f2bf(a.Wh[base + 256 * i]);
        } else {                             // zero pad rows (child idx 512)
            for (int i = tid; i < 512; i += 256) {
                a.hbf[(size_t)512 * 512 + i] = 0;
                a.hbf[(size_t)1025 * 512 + i] = 0;
                a.cbuf[(size_t)512 * 512 + i] = 0.f;
                a.cbuf[(size_t)1025 * 512 + i] = 0.f;
            }
        }
        __syncthreads();                     // ts reusable next iteration
    }
    grid.sync();

    // ---- stage B: xcat[1024][2048] = bf16(emb[tok]) @ WxT^T + bias ----
    for (int t = bid; t < 256; t += G) {
        const int mt = t & 31, nb = t >> 5;
        const int w = tid >> 6, lane = tid & 63;
        const int m = lane & 15, q = lane >> 4;
        const int colbase = nb * 256 + w * 64;
        const int r0 = mt * 32 + m, r1 = r0 + 16;
        const int tok0 = (r0 < 512) ? a.lin[r0] : a.rin[r0 - 512];
        const int tok1 = (r1 < 512) ? a.lin[r1] : a.rin[r1 - 512];
        const float* A0 = a.emb + (size_t)tok0 * 512;
        const float* A1 = a.emb + (size_t)tok1 * 512;

        f32x4 acc[2][4];
#pragma unroll
        for (int i = 0; i < 2; ++i)
#pragma unroll
            for (int j = 0; j < 4; ++j) acc[i][j] = (f32x4){0.f, 0.f, 0.f, 0.f};

        for (int k0 = 0; k0 < 512; k0 += 32) {
            const int koff = k0 + q * 8;
            bf16x8 a0 = load_f32_as_bf8(A0 + koff);
            bf16x8 a1 = load_f32_as_bf8(A1 + koff);
#pragma unroll
            for (int jj = 0; jj < 4; ++jj) {
                bf16x8 b = *(const bf16x8*)(a.WxT + (size_t)(colbase + jj * 16 + m) * 512 + koff);
                acc[0][jj] = mfma16(a0, b, acc[0][jj]);
                acc[1][jj] = mfma16(a1, b, acc[1][jj]);
            }
        }
#pragma unroll
        for (int i = 0; i < 2; ++i)
#pragma unroll
            for (int jj = 0; jj < 4; ++jj)
#pragma unroll
                for (int rr = 0; rr < 4; ++rr) {
                    const int R = mt * 32 + i * 16 + q * 4 + rr;
                    const int col = colbase + jj * 16 + m;
                    const float bias = (col < 1536) ? a.b_ioux[col] : a.b_fx[col - 1536];
                    a.xcat[(size_t)R * 2048 + col] = f2bf(acc[i][jj][rr] + bias);
                }
    }
    grid.sync();

    // ---- stage C0: leaf gating (children all pad-zero; GEMM acc == 0) ----
    for (int r = bid; r < 342; r += G) {
        const int tree = (r >= 171) ? 1 : 0;
        const int j = r - tree * 171;
        const unsigned short* xr = a.xcat + (size_t)(tree * 512 + j) * 2048;
        float* cb = a.cbuf + (size_t)tree * 513 * 512;
        unsigned short* hb = a.hbf + (size_t)tree * 513 * 512;
#pragma unroll
        for (int u = 0; u < 2; ++u) {
            const int col = tid + u * 256;
            const float ig = sigm(bf2f(xr[col]) + a.b_iouh[col]);
            const float og = sigm(bf2f(xr[512 + col]) + a.b_iouh[512 + col]);
            const float ug = tanhf(bf2f(xr[1024 + col]) + a.b_iouh[1024 + col]);
            const float cv = ig * ug;
            cb[(size_t)j * 512 + col] = cv;
            hb[(size_t)j * 512 + col] = f2bf(og * tanhf(cv));
        }
    }
    grid.sync();

    // ---- phases d4..root: fused gather+GEMM, then gating ----
    static const int los[5] = {171, 427, 491, 507, 511};
    static const int Bs[5]  = {256, 64, 16, 4, 1};
    for (int ph = 0; ph < 5; ++ph) {
        const int lo = los[ph], B = Bs[ph], B2 = 2 * B;
        const int mti1 = (B2 + 31) >> 5, mti2 = (4 * B2 + 31) >> 5;
        const int nti1 = mti1 * 6;
        const int ntot = nti1 + mti2 * 2;
        for (int t = bid; t < ntot; t += G)
            gemm_task(t, lo, B, mti1, nti1, mti2, a);
        grid.sync();
        if (ph < 4) {
            for (int r = bid; r < B2; r += G)
                gate_row(r, lo, B, a);
            grid.sync();
        }
    }

    // ---- finale (block 0): root gating + similarity head, fully fused ----
    if (bid == 0) {
        __shared__ float sv[1024];
        // root cell states (og/h not needed: head consumes CELL states)
#pragma unroll
        for (int tree = 0; tree < 2; ++tree) {
            const int* ch = (tree ? a.rch : a.lch) + 4 * 511;
            const float* cb = a.cbuf + (size_t)tree * 513 * 512;
            const float* ir = a.ioub + (size_t)tree * 1536;
            const float* fr = a.fpre + (size_t)tree * 4 * 512;
            const int c0 = ch[0], c1 = ch[1], c2 = ch[2], c3 = ch[3];
#pragma unroll
            for (int u = 0; u < 2; ++u) {
                const int col = tid + u * 256;
                const float ig = sigm(ir[col]);
                const float ug = tanhf(ir[1024 + col]);
                const float cv = ig * ug
                    + sigm(fr[col])        * cb[(size_t)c0 * 512 + col]
                    + sigm(fr[512 + col])  * cb[(size_t)c1 * 512 + col]
                    + sigm(fr[1024 + col]) * cb[(size_t)c2 * 512 + col]
                    + sigm(fr[1536 + col]) * cb[(size_t)c3 * 512 + col];
                sv[tree * 512 + col] = cv;
            }
        }
        __syncthreads();
        // vec = [lc*rc, |lc-rc|] in place
#pragma unroll
        for (int u = 0; u < 2; ++u) {
            const int k = tid + u * 256;
            if (k < 512) {
                const float lcv = sv[k], rcv = sv[512 + k];
                sv[k] = lcv * rcv;
                sv[512 + k] = fabsf(lcv - rcv);
            }
        }
        __syncthreads();
        // hid = sigmoid(vec @ Wh + bh); each thread owns cols 2t, 2t+1
        float a0 = 0.f, a1 = 0.f;
        for (int k = 0; k < 1024; ++k) {
            const unsigned int wv = *(const unsigned int*)(a.Whb + (size_t)k * 512 + 2 * tid);
            const float s = sv[k];
            a0 += s * bf2f((unsigned short)(wv & 0xffffu));
            a1 += s * bf2f((unsigned short)(wv >> 16));
        }
        const float h0 = sigm(a0 + a.bh[2 * tid]);
        const float h1 = sigm(a1 + a.bh[2 * tid + 1]);
        float lp[5];
#pragma unroll
        for (int cc = 0; cc < 5; ++cc)
            lp[cc] = h0 * a.Wp[(size_t)(2 * tid) * 5 + cc]
                   + h1 * a.Wp[(size_t)(2 * tid + 1) * 5 + cc];
#pragma unroll
        for (int cc = 0; cc < 5; ++cc)
#pragma unroll
            for (int off = 32; off; off >>= 1)
                lp[cc] += __shfl_xor(lp[cc], off, 64);
        __shared__ float red[4][5];
        const int w = tid >> 6, lane = tid & 63;
        if (lane == 0)
#pragma unroll
            for (int cc = 0; cc < 5; ++cc) red[w][cc] = lp[cc];
        __syncthreads();
        if (tid == 0) {
            float lg[5], mx = -1e30f;
#pragma unroll
            for (int cc = 0; cc < 5; ++cc) {
                lg[cc] = red[0][cc] + red[1][cc] + red[2][cc] + red[3][cc] + a.bp[cc];
                mx = fmaxf(mx, lg[cc]);
            }
            float s = 0.f;
#pragma unroll
            for (int cc = 0; cc < 5; ++cc) s += __expf(lg[cc] - mx);
            const float lse = mx + __logf(s);
#pragma unroll
            for (int cc = 0; cc < 5; ++cc) a.out[cc] = lg[cc] - lse;
        }
    }
}

// ---------------- launch ----------------------------------------------------
extern "C" void kernel_launch(void* const* d_in, const int* in_sizes, int n_in,
                              void* d_out, int out_size, void* d_ws, size_t ws_size,
                              hipStream_t stream)
{
    (void)ws_size; (void)n_in; (void)in_sizes; (void)out_size;

    Args ha;
    ha.lin     = (const int*)d_in[0];
    ha.rin     = (const int*)d_in[1];
    ha.lch     = (const int*)d_in[2];
    ha.rch     = (const int*)d_in[3];
    ha.emb     = (const float*)d_in[4];
    ha.W_ioux  = (const float*)d_in[5];
    ha.b_ioux  = (const float*)d_in[6];
    ha.W_iouh  = (const float*)d_in[7];
    ha.b_iouh  = (const float*)d_in[8];
    ha.W_fx    = (const float*)d_in[9];
    ha.b_fx    = (const float*)d_in[10];
    ha.W_fh    = (const float*)d_in[11];
    ha.b_fh    = (const float*)d_in[12];
    ha.Wh      = (const float*)d_in[13];
    ha.bh      = (const float*)d_in[14];
    ha.Wp      = (const float*)d_in[15];
    ha.bp      = (const float*)d_in[16];
    ha.out     = (float*)d_out;

    char* p = (char*)d_ws;
    ha.WiouhT = (unsigned short*)p;  p += (size_t)1536 * 512 * 2;
    ha.WfhT   = (unsigned short*)p;  p += (size_t)512 * 512 * 2;
    ha.WxT    = (unsigned short*)p;  p += (size_t)2048 * 512 * 2;
    ha.Whb    = (unsigned short*)p;  p += (size_t)1024 * 512 * 2;
    ha.xcat   = (unsigned short*)p;  p += (size_t)1024 * 2048 * 2;
    ha.hbf    = (unsigned short*)p;  p += (size_t)2 * 513 * 512 * 2;
    ha.cbuf   = (float*)p;           p += (size_t)2 * 513 * 512 * 4;
    ha.ioub   = (float*)p;           p += (size_t)512 * 1536 * 4;
    ha.fpre   = (float*)p;           p += (size_t)2048 * 512 * 4;

    void* kargs[] = { &ha };
    hipLaunchCooperativeKernel((const void*)mega, dim3(GRID), dim3(256),
                               kargs, 0, stream);
}

// Round 2
// 630.644 us; speedup vs baseline: 1.1660x; 1.1660x over previous
//
#include <hip/hip_runtime.h>
#include <math.h>

// SimilarityTreeLSTM on MI355X — round 4: persistent cooperative kernel with
// HAND-ROLLED grid barrier.
//
// Round-3 post-mortem: cg::grid.sync() costs ~45us each on gfx950 (ockl
// implementation: long s_sleep backoff + heavyweight fencing). 12 syncs ~=
// 540us of the 554us mega duration; all utilization counters near zero.
// This round: same stage structure, same numerics, but each grid sync is a
// one-shot device-scope counter barrier:
//   arrive: __threadfence() (wbl2+inv, cross-XCD per guide G16) + relaxed
//           agent fetch_add; wait: relaxed agent poll + s_sleep(1);
//           acquire: __threadfence().
// Counters are one-per-barrier-instance (no reset/generation hazards). ws is
// re-poisoned 0xAA each call, so block 0 zero-inits the counters and releases
// a magic 'ready' flag all blocks check once at entry.
//
// Level decomposition (deterministic from _build_children(512,4), j = 511-i):
//   leaves [0,171) | d4 [171,427) | d3 [427,491) | d2 [491,507)
//   | d1 [507,511) | root [511,512)
// Pad child index 512 maps to a per-tree zero row ([2][513][512] state bufs).
//
// MFMA: v_mfma_f32_16x16x32_bf16. A-frag: lane holds A[m=lane&15][k=q*8+j],
// B-frag: B[k=q*8+j][n=lane&15] (W stored transposed -> 16B contiguous load),
// C/D: col=lane&15, row=q*4+reg.  [per guide §3, verified]

typedef __attribute__((ext_vector_type(8))) __bf16 bf16x8;
typedef __attribute__((ext_vector_type(4))) float f32x4;

#define GRID 256
#define READY_MAGIC 0x13579BDFu

__device__ __forceinline__ float sigm(float x) { return 1.0f / (1.0f + __expf(-x)); }

__device__ __forceinline__ unsigned short f2bf(float f) {
    union { float f; unsigned int u; } v; v.f = f;
    unsigned int r = v.u + 0x7FFF + ((v.u >> 16) & 1);
    return (unsigned short)(r >> 16);
}
__device__ __forceinline__ float bf2f(unsigned short b) {
    union { unsigned int u; float f; } v; v.u = ((unsigned int)b) << 16;
    return v.f;
}
__device__ __forceinline__ f32x4 mfma16(bf16x8 a, bf16x8 b, f32x4 c) {
    return __builtin_amdgcn_mfma_f32_16x16x32_bf16(a, b, c, 0, 0, 0);
}
__device__ __forceinline__ bf16x8 load_f32_as_bf8(const float* p) {
    float4 x = *(const float4*)p;
    float4 y = *(const float4*)(p + 4);
    bf16x8 r;
    r[0] = (__bf16)x.x; r[1] = (__bf16)x.y; r[2] = (__bf16)x.z; r[3] = (__bf16)x.w;
    r[4] = (__bf16)y.x; r[5] = (__bf16)y.y; r[6] = (__bf16)y.z; r[7] = (__bf16)y.w;
    return r;
}

struct Args {
    const int   *lin, *rin, *lch, *rch;
    const float *emb;
    const float *W_ioux, *b_ioux, *W_iouh, *b_iouh;
    const float *W_fx, *b_fx, *W_fh, *b_fh;
    const float *Wh, *bh, *Wp, *bp;
    unsigned short *WiouhT, *WfhT, *WxT, *Whb, *xcat, *hbf;
    float *cbuf, *ioub, *fpre, *out;
    unsigned *bars;        // [32] one-shot barrier counters; [31] = ready flag
};

// ---- fast one-shot grid barrier (counter idx used exactly once per call) ---
__device__ __forceinline__ void grid_bar(unsigned* bars, int idx, int nb)
{
    __syncthreads();                       // wave stores drained (vmcnt(0))
    if (threadIdx.x == 0) {
        __threadfence();                   // release: wbl2 -> L3, agent scope
        __hip_atomic_fetch_add(&bars[idx], 1u, __ATOMIC_RELAXED,
                               __HIP_MEMORY_SCOPE_AGENT);
        while (__hip_atomic_load(&bars[idx], __ATOMIC_RELAXED,
                                 __HIP_MEMORY_SCOPE_AGENT) < (unsigned)nb)
            __builtin_amdgcn_s_sleep(1);
        __threadfence();                   // acquire: inv L1/L2, fresh reads
    }
    __syncthreads();
}

// 32x32 fp32->bf16 transpose tile via LDS
__device__ __forceinline__
void ttile(const float* __restrict__ src, int lds_, unsigned short* __restrict__ dst,
           int ldd, int k0, int n0, float (*ts)[33], int tid)
{
    const int tx = tid & 31, ty = tid >> 5;
#pragma unroll
    for (int i = 0; i < 4; ++i)
        ts[ty + 8 * i][tx] = src[(size_t)(k0 + ty + 8 * i) * lds_ + n0 + tx];
    __syncthreads();
#pragma unroll
    for (int i = 0; i < 4; ++i)
        dst[(size_t)(n0 + ty + 8 * i) * ldd + k0 + tx] = f2bf(ts[tx][ty + 8 * i]);
}

// -------- per-phase fused gather + dual GEMM (one block-task) --------------
__device__ __forceinline__
void gemm_task(int t, int lo, int B, int mti1, int nti1, int mti2, const Args& a)
{
    const int B2 = 2 * B;
    const int tid = threadIdx.x, w = tid >> 6, lane = tid & 63;
    const int m = lane & 15, q = lane >> 4;

    if (t < nti1) {
        // iou: [B2,512] (child-h sum, gathered on the fly) x [512,1536]
        const int mt = t % mti1, nb = t / mti1;
        const int colbase = nb * 256 + w * 64;
        const unsigned short* pA[2][4];
#pragma unroll
        for (int i = 0; i < 2; ++i) {
            const int r = mt * 32 + m + i * 16;
            int c[4] = {512, 512, 512, 512};
            int tree = 0;
            if (r < B2) {
                tree = (r >= B) ? 1 : 0;
                const int j = lo + r - tree * B;
                const int* ch = (tree ? a.rch : a.lch) + 4 * j;
                c[0] = ch[0]; c[1] = ch[1]; c[2] = ch[2]; c[3] = ch[3];
            }
            const unsigned short* hb = a.hbf + (size_t)tree * 513 * 512;
#pragma unroll
            for (int s = 0; s < 4; ++s) pA[i][s] = hb + (size_t)c[s] * 512;
        }
        f32x4 acc[2][4];
#pragma unroll
        for (int i = 0; i < 2; ++i)
#pragma unroll
            for (int j = 0; j < 4; ++j) acc[i][j] = (f32x4){0.f, 0.f, 0.f, 0.f};

        for (int k0 = 0; k0 < 512; k0 += 32) {
            const int koff = k0 + q * 8;
            bf16x8 af[2];
#pragma unroll
            for (int i = 0; i < 2; ++i) {
                float s[8] = {0.f, 0.f, 0.f, 0.f, 0.f, 0.f, 0.f, 0.f};
#pragma unroll
                for (int cc = 0; cc < 4; ++cc) {
                    bf16x8 v = *(const bf16x8*)(pA[i][cc] + koff);
#pragma unroll
                    for (int j = 0; j < 8; ++j) s[j] += (float)v[j];
                }
                bf16x8 av;
#pragma unroll
                for (int j = 0; j < 8; ++j) av[j] = (__bf16)s[j];
                af[i] = av;
            }
#pragma unroll
            for (int jj = 0; jj < 4; ++jj) {
                bf16x8 b = *(const bf16x8*)(a.WiouhT + (size_t)(colbase + jj * 16 + m) * 512 + koff);
                acc[0][jj] = mfma16(af[0], b, acc[0][jj]);
                acc[1][jj] = mfma16(af[1], b, acc[1][jj]);
            }
        }
#pragma unroll
        for (int i = 0; i < 2; ++i)
#pragma unroll
            for (int jj = 0; jj < 4; ++jj)
#pragma unroll
                for (int rr = 0; rr < 4; ++rr) {
                    const int R = mt * 32 + i * 16 + q * 4 + rr;
                    if (R < B2) {
                        const int tr = (R >= B) ? 1 : 0;
                        const int jR = lo + R - tr * B;
                        const int col = colbase + jj * 16 + m;
                        a.ioub[(size_t)R * 1536 + col] = acc[i][jj][rr] + a.b_iouh[col]
                            + bf2f(a.xcat[(size_t)(tr * 512 + jR) * 2048 + col]);
                    }
                }
    } else {
        // f: [4*B2,512] (child h rows, direct) x [512,512]
        t -= nti1;
        const int mt = t % mti2, nb = t / mti2;
        const int colbase = nb * 256 + w * 64;
        const unsigned short* pA[2];
#pragma unroll
        for (int i = 0; i < 2; ++i) {
            const int rf = mt * 32 + m + i * 16;
            int tree = 0, c = 512;
            if (rf < 4 * B2) {
                const int r = rf >> 2, s = rf & 3;
                tree = (r >= B) ? 1 : 0;
                const int j = lo + r - tree * B;
                c = ((tree ? a.rch : a.lch) + 4 * j)[s];
            }
            pA[i] = a.hbf + ((size_t)tree * 513 + c) * 512;
        }
        f32x4 acc[2][4];
#pragma unroll
        for (int i = 0; i < 2; ++i)
#pragma unroll
            for (int j = 0; j < 4; ++j) acc[i][j] = (f32x4){0.f, 0.f, 0.f, 0.f};

        for (int k0 = 0; k0 < 512; k0 += 32) {
            const int koff = k0 + q * 8;
            bf16x8 a0 = *(const bf16x8*)(pA[0] + koff);
            bf16x8 a1 = *(const bf16x8*)(pA[1] + koff);
#pragma unroll
            for (int jj = 0; jj < 4; ++jj) {
                bf16x8 b = *(const bf16x8*)(a.WfhT + (size_t)(colbase + jj * 16 + m) * 512 + koff);
                acc[0][jj] = mfma16(a0, b, acc[0][jj]);
                acc[1][jj] = mfma16(a1, b, acc[1][jj]);
            }
        }
#pragma unroll
        for (int i = 0; i < 2; ++i)
#pragma unroll
            for (int jj = 0; jj < 4; ++jj)
#pragma unroll
                for (int rr = 0; rr < 4; ++rr) {
                    const int R = mt * 32 + i * 16 + q * 4 + rr;
                    if (R < 4 * B2) {
                        const int rR = R >> 2;
                        const int tr = (rR >= B) ? 1 : 0;
                        const int jR = lo + rR - tr * B;
                        const int col = colbase + jj * 16 + m;
                        a.fpre[(size_t)R * 512 + col] = acc[i][jj][rr] + a.b_fh[col]
                            + bf2f(a.xcat[(size_t)(tr * 512 + jR) * 2048 + 1536 + col]);
                    }
                }
    }
}

// -------- general gating for one node row (writes c fp32, h bf16) ----------
__device__ __forceinline__
void gate_row(int r, int lo, int B, const Args& a)
{
    const int tid = threadIdx.x;
    const int tree = (r >= B) ? 1 : 0;
    const int j = lo + r - tree * B;
    const int* ch = (tree ? a.rch : a.lch) + 4 * j;
    const int c0 = ch[0], c1 = ch[1], c2 = ch[2], c3 = ch[3];
    float* cb = a.cbuf + (size_t)tree * 513 * 512;
    unsigned short* hb = a.hbf + (size_t)tree * 513 * 512;
    const float* ir = a.ioub + (size_t)r * 1536;
    const float* fr = a.fpre + (size_t)r * 4 * 512;
#pragma unroll
    for (int u = 0; u < 2; ++u) {
        const int col = tid + u * 256;
        const float ig = sigm(ir[col]);
        const float og = sigm(ir[512 + col]);
        const float ug = tanhf(ir[1024 + col]);
        float cv = ig * ug
            + sigm(fr[col])        * cb[(size_t)c0 * 512 + col]
            + sigm(fr[512 + col])  * cb[(size_t)c1 * 512 + col]
            + sigm(fr[1024 + col]) * cb[(size_t)c2 * 512 + col]
            + sigm(fr[1536 + col]) * cb[(size_t)c3 * 512 + col];
        cb[(size_t)j * 512 + col] = cv;
        hb[(size_t)j * 512 + col] = f2bf(og * tanhf(cv));
    }
}

// ---------------------------- the mega-kernel ------------------------------
__global__ __launch_bounds__(256, 1)
void mega(Args a)
{
    const int tid = threadIdx.x, bid = blockIdx.x;
    const int G = gridDim.x;
    __shared__ float ts[32][33];

    // ---- barrier init: ws is poisoned 0xAA each call ----
    if (bid == 0 && tid == 0) {
        for (int i = 0; i < 31; ++i)
            __hip_atomic_store(&a.bars[i], 0u, __ATOMIC_RELAXED,
                               __HIP_MEMORY_SCOPE_AGENT);
        __threadfence();
        __hip_atomic_store(&a.bars[31], READY_MAGIC, __ATOMIC_RELEASE,
                           __HIP_MEMORY_SCOPE_AGENT);
    }
    if (tid == 0) {
        while (__hip_atomic_load(&a.bars[31], __ATOMIC_RELAXED,
                                 __HIP_MEMORY_SCOPE_AGENT) != READY_MAGIC)
            __builtin_amdgcn_s_sleep(1);
        __threadfence();
    }
    __syncthreads();
    int bi = 0;   // barrier index (uniform across blocks)

    // ---- stage A: weight transpose/convert + zero pad rows (2305 tasks) ----
    for (int t = bid; t < 2305; t += G) {
        if (t < 768) {                       // W_iouh [512][1536] -> WiouhT
            ttile(a.W_iouh, 1536, a.WiouhT, 512, (t & 15) * 32, (t >> 4) * 32, ts, tid);
        } else if (t < 1024) {               // W_fh -> WfhT
            const int tt = t - 768;
            ttile(a.W_fh, 512, a.WfhT, 512, (tt & 15) * 32, (tt >> 4) * 32, ts, tid);
        } else if (t < 1792) {               // W_ioux -> WxT rows [0,1536)
            const int tt = t - 1024;
            ttile(a.W_ioux, 1536, a.WxT, 512, (tt & 15) * 32, (tt >> 4) * 32, ts, tid);
        } else if (t < 2048) {               // W_fx -> WxT rows [1536,2048)
            const int tt = t - 1792;
            ttile(a.W_fx, 512, a.WxT + (size_t)1536 * 512, 512, (tt & 15) * 32, (tt >> 4) * 32, ts, tid);
        } else if (t < 2304) {               // Wh -> bf16 copy
            size_t base = (size_t)(t - 2048) * 2048 + tid;
#pragma unroll
            for (int i = 0; i < 8; ++i) a.Whb[base + 256 * i] = f2bf(a.Wh[base + 256 * i]);
        } else {                             // zero pad rows (child idx 512)
            for (int i = tid; i < 512; i += 256) {
                a.hbf[(size_t)512 * 512 + i] = 0;
                a.hbf[(size_t)1025 * 512 + i] = 0;
                a.cbuf[(size_t)512 * 512 + i] = 0.f;
                a.cbuf[(size_t)1025 * 512 + i] = 0.f;
            }
        }
        __syncthreads();                     // ts reusable next iteration
    }
    grid_bar(a.bars, bi++, G);

    // ---- stage B: xcat[1024][2048] = bf16(emb[tok]) @ WxT^T + bias ----
    for (int t = bid; t < 256; t += G) {
        const int mt = t & 31, nb = t >> 5;
        const int w = tid >> 6, lane = tid & 63;
        const int m = lane & 15, q = lane >> 4;
        const int colbase = nb * 256 + w * 64;
        const int r0 = mt * 32 + m, r1 = r0 + 16;
        const int tok0 = (r0 < 512) ? a.lin[r0] : a.rin[r0 - 512];
        const int tok1 = (r1 < 512) ? a.lin[r1] : a.rin[r1 - 512];
        const float* A0 = a.emb + (size_t)tok0 * 512;
        const float* A1 = a.emb + (size_t)tok1 * 512;

        f32x4 acc[2][4];
#pragma unroll
        for (int i = 0; i < 2; ++i)
#pragma unroll
            for (int j = 0; j < 4; ++j) acc[i][j] = (f32x4){0.f, 0.f, 0.f, 0.f};

        for (int k0 = 0; k0 < 512; k0 += 32) {
            const int koff = k0 + q * 8;
            bf16x8 a0 = load_f32_as_bf8(A0 + koff);
            bf16x8 a1 = load_f32_as_bf8(A1 + koff);
#pragma unroll
            for (int jj = 0; jj < 4; ++jj) {
                bf16x8 b = *(const bf16x8*)(a.WxT + (size_t)(colbase + jj * 16 + m) * 512 + koff);
                acc[0][jj] = mfma16(a0, b, acc[0][jj]);
                acc[1][jj] = mfma16(a1, b, acc[1][jj]);
            }
        }
#pragma unroll
        for (int i = 0; i < 2; ++i)
#pragma unroll
            for (int jj = 0; jj < 4; ++jj)
#pragma unroll
                for (int rr = 0; rr < 4; ++rr) {
                    const int R = mt * 32 + i * 16 + q * 4 + rr;
                    const int col = colbase + jj * 16 + m;
                    const float bias = (col < 1536) ? a.b_ioux[col] : a.b_fx[col - 1536];
                    a.xcat[(size_t)R * 2048 + col] = f2bf(acc[i][jj][rr] + bias);
                }
    }
    grid_bar(a.bars, bi++, G);

    // ---- stage C0: leaf gating (children all pad-zero; GEMM acc == 0) ----
    for (int r = bid; r < 342; r += G) {
        const int tree = (r >= 171) ? 1 : 0;
        const int j = r - tree * 171;
        const unsigned short* xr = a.xcat + (size_t)(tree * 512 + j) * 2048;
        float* cb = a.cbuf + (size_t)tree * 513 * 512;
        unsigned short* hb = a.hbf + (size_t)tree * 513 * 512;
#pragma unroll
        for (int u = 0; u < 2; ++u) {
            const int col = tid + u * 256;
            const float ig = sigm(bf2f(xr[col]) + a.b_iouh[col]);
            const float og = sigm(bf2f(xr[512 + col]) + a.b_iouh[512 + col]);
            const float ug = tanhf(bf2f(xr[1024 + col]) + a.b_iouh[1024 + col]);
            const float cv = ig * ug;
            cb[(size_t)j * 512 + col] = cv;
            hb[(size_t)j * 512 + col] = f2bf(og * tanhf(cv));
        }
    }
    grid_bar(a.bars, bi++, G);

    // ---- phases d4..root: fused gather+GEMM, then gating ----
    static const int los[5] = {171, 427, 491, 507, 511};
    static const int Bs[5]  = {256, 64, 16, 4, 1};
    for (int ph = 0; ph < 5; ++ph) {
        const int lo = los[ph], B = Bs[ph], B2 = 2 * B;
        const int mti1 = (B2 + 31) >> 5, mti2 = (4 * B2 + 31) >> 5;
        const int nti1 = mti1 * 6;
        const int ntot = nti1 + mti2 * 2;
        for (int t = bid; t < ntot; t += G)
            gemm_task(t, lo, B, mti1, nti1, mti2, a);
        grid_bar(a.bars, bi++, G);
        if (ph < 4) {
            for (int r = bid; r < B2; r += G)
                gate_row(r, lo, B, a);
            grid_bar(a.bars, bi++, G);
        }
    }

    // ---- finale (block 0): root gating + similarity head, fully fused ----
    if (bid == 0) {
        __shared__ float sv[1024];
        // root cell states (og/h not needed: head consumes CELL states)
#pragma unroll
        for (int tree = 0; tree < 2; ++tree) {
            const int* ch = (tree ? a.rch : a.lch) + 4 * 511;
            const float* cb = a.cbuf + (size_t)tree * 513 * 512;
            const float* ir = a.ioub + (size_t)tree * 1536;
            const float* fr = a.fpre + (size_t)tree * 4 * 512;
            const int c0 = ch[0], c1 = ch[1], c2 = ch[2], c3 = ch[3];
#pragma unroll
            for (int u = 0; u < 2; ++u) {
                const int col = tid + u * 256;
                const float ig = sigm(ir[col]);
                const float ug = tanhf(ir[1024 + col]);
                const float cv = ig * ug
                    + sigm(fr[col])        * cb[(size_t)c0 * 512 + col]
                    + sigm(fr[512 + col])  * cb[(size_t)c1 * 512 + col]
                    + sigm(fr[1024 + col]) * cb[(size_t)c2 * 512 + col]
                    + sigm(fr[1536 + col]) * cb[(size_t)c3 * 512 + col];
                sv[tree * 512 + col] = cv;
            }
        }
        __syncthreads();
        // vec = [lc*rc, |lc-rc|] in place
#pragma unroll
        for (int u = 0; u < 2; ++u) {
            const int k = tid + u * 256;
            if (k < 512) {
                const float lcv = sv[k], rcv = sv[512 + k];
                sv[k] = lcv * rcv;
                sv[512 + k] = fabsf(lcv - rcv);
            }
        }
        __syncthreads();
        // hid = sigmoid(vec @ Wh + bh); each thread owns cols 2t, 2t+1
        float a0 = 0.f, a1 = 0.f;
        for (int k = 0; k < 1024; ++k) {
            const unsigned int wv = *(const unsigned int*)(a.Whb + (size_t)k * 512 + 2 * tid);
            const float s = sv[k];
            a0 += s * bf2f((unsigned short)(wv & 0xffffu));
            a1 += s * bf2f((unsigned short)(wv >> 16));
        }
        const float h0 = sigm(a0 + a.bh[2 * tid]);
        const float h1 = sigm(a1 + a.bh[2 * tid + 1]);
        float lp[5];
#pragma unroll
        for (int cc = 0; cc < 5; ++cc)
            lp[cc] = h0 * a.Wp[(size_t)(2 * tid) * 5 + cc]
                   + h1 * a.Wp[(size_t)(2 * tid + 1) * 5 + cc];
#pragma unroll
        for (int cc = 0; cc < 5; ++cc)
#pragma unroll
            for (int off = 32; off; off >>= 1)
                lp[cc] += __shfl_xor(lp[cc], off, 64);
        __shared__ float red[4][5];
        const int w = tid >> 6, lane = tid & 63;
        if (lane == 0)
#pragma unroll
            for (int cc = 0; cc < 5; ++cc) red[w][cc] = lp[cc];
        __syncthreads();
        if (tid == 0) {
            float lg[5], mx = -1e30f;
#pragma unroll
            for (int cc = 0; cc < 5; ++cc) {
                lg[cc] = red[0][cc] + red[1][cc] + red[2][cc] + red[3][cc] + a.bp[cc];
                mx = fmaxf(mx, lg[cc]);
            }
            float s = 0.f;
#pragma unroll
            for (int cc = 0; cc < 5; ++cc) s += __expf(lg[cc] - mx);
            const float lse = mx + __logf(s);
#pragma unroll
            for (int cc = 0; cc < 5; ++cc) a.out[cc] = lg[cc] - lse;
        }
    }
}

// ---------------- launch ----------------------------------------------------
extern "C" void kernel_launch(void* const* d_in, const int* in_sizes, int n_in,
                              void* d_out, int out_size, void* d_ws, size_t ws_size,
                              hipStream_t stream)
{
    (void)ws_size; (void)n_in; (void)in_sizes; (void)out_size;

    Args ha;
    ha.lin     = (const int*)d_in[0];
    ha.rin     = (const int*)d_in[1];
    ha.lch     = (const int*)d_in[2];
    ha.rch     = (const int*)d_in[3];
    ha.emb     = (const float*)d_in[4];
    ha.W_ioux  = (const float*)d_in[5];
    ha.b_ioux  = (const float*)d_in[6];
    ha.W_iouh  = (const float*)d_in[7];
    ha.b_iouh  = (const float*)d_in[8];
    ha.W_fx    = (const float*)d_in[9];
    ha.b_fx    = (const float*)d_in[10];
    ha.W_fh    = (const float*)d_in[11];
    ha.b_fh    = (const float*)d_in[12];
    ha.Wh      = (const float*)d_in[13];
    ha.bh      = (const float*)d_in[14];
    ha.Wp      = (const float*)d_in[15];
    ha.bp      = (const float*)d_in[16];
    ha.out     = (float*)d_out;

    char* p = (char*)d_ws;
    ha.WiouhT = (unsigned short*)p;  p += (size_t)1536 * 512 * 2;
    ha.WfhT   = (unsigned short*)p;  p += (size_t)512 * 512 * 2;
    ha.WxT    = (unsigned short*)p;  p += (size_t)2048 * 512 * 2;
    ha.Whb    = (unsigned short*)p;  p += (size_t)1024 * 512 * 2;
    ha.xcat   = (unsigned short*)p;  p += (size_t)1024 * 2048 * 2;
    ha.hbf    = (unsigned short*)p;  p += (size_t)2 * 513 * 512 * 2;
    ha.cbuf   = (float*)p;           p += (size_t)2 * 513 * 512 * 4;
    ha.ioub   = (float*)p;           p += (size_t)512 * 1536 * 4;
    ha.fpre   = (float*)p;           p += (size_t)2048 * 512 * 4;
    ha.bars   = (unsigned*)p;        p += (size_t)32 * 4;

    void* kargs[] = { &ha };
    hipLaunchCooperativeKernel((const void*)mega, dim3(GRID), dim3(256),
                               kargs, 0, stream);
}

// Round 3
// 567.891 us; speedup vs baseline: 1.2949x; 1.1105x over previous
//
#include <hip/hip_runtime.h>
#include <math.h>

// SimilarityTreeLSTM on MI355X — round 5: fence-free grid barriers via
// coherent (agent-scope) accesses to all cross-block mutable data.
//
// Round-4 post-mortem: both cg::grid.sync (46us) and a hand-rolled barrier
// with __threadfence (38us) pay ~35us/barrier because EVERY block executes
// buffer_wbl2/buffer_inv (L2 writeback+invalidate walk); 32 blocks per XCD
// serialize on the L2. Fix: move coherence from the barrier to the accesses.
//   * mutable shared tensors (hbf, cbuf, ioub, fpre): relaxed AGENT-scope
//     atomic loads/stores (compile to global_load/store sc0 sc1 -> L3
//     coherence point; no dirty L2 lines, no stale L1/L2 reads).
//   * write-once tensors (WiouhT/WfhT/WxT/Whb, xcat): WRITTEN with agent
//     atomics (land clean in L3), READ with normal cached loads (never
//     overwritten; caches clean at dispatch start due to end-of-kernel
//     flush of the preceding poison-fill dispatch).
//   * barrier: __syncthreads (drains vmcnt->stores at L3) + relaxed agent
//     fetch_add + relaxed poll + s_sleep(1). No wbl2, no inv.
// Stores packed to 4/8B: lane-pair __shfl_xor packing in GEMM epilogues,
// 2-cols-per-thread restructure in gating/transpose.
//
// Level decomposition (deterministic from _build_children(512,4), j = 511-i):
//   leaves [0,171) | d4 [171,427) | d3 [427,491) | d2 [491,507)
//   | d1 [507,511) | root [511,512)
// Pad child index 512 maps to a per-tree zero row ([2][513][512] state bufs).
//
// MFMA: v_mfma_f32_16x16x32_bf16. A-frag: lane holds A[m=lane&15][k=q*8+j],
// B-frag: B[k=q*8+j][n=lane&15] (W stored transposed -> 16B contiguous load),
// C/D: col=lane&15, row=q*4+reg.  [per guide §3, verified]

typedef __attribute__((ext_vector_type(8))) __bf16 bf16x8;
typedef __attribute__((ext_vector_type(4))) float f32x4;
typedef unsigned long long u64;

#define GRID 256
#define READY_MAGIC 0x13579BDFu

__device__ __forceinline__ float sigm(float x) { return 1.0f / (1.0f + __expf(-x)); }

__device__ __forceinline__ unsigned short f2bf(float f) {
    union { float f; unsigned int u; } v; v.f = f;
    unsigned int r = v.u + 0x7FFF + ((v.u >> 16) & 1);
    return (unsigned short)(r >> 16);
}
__device__ __forceinline__ float bf2f(unsigned short b) {
    union { unsigned int u; float f; } v; v.u = ((unsigned int)b) << 16;
    return v.f;
}
__device__ __forceinline__ f32x4 mfma16(bf16x8 a, bf16x8 b, f32x4 c) {
    return __builtin_amdgcn_mfma_f32_16x16x32_bf16(a, b, c, 0, 0, 0);
}
__device__ __forceinline__ bf16x8 load_f32_as_bf8(const float* p) {
    float4 x = *(const float4*)p;
    float4 y = *(const float4*)(p + 4);
    bf16x8 r;
    r[0] = (__bf16)x.x; r[1] = (__bf16)x.y; r[2] = (__bf16)x.z; r[3] = (__bf16)x.w;
    r[4] = (__bf16)y.x; r[5] = (__bf16)y.y; r[6] = (__bf16)y.z; r[7] = (__bf16)y.w;
    return r;
}

// ---- coherent (agent-scope, relaxed) access helpers -----------------------
__device__ __forceinline__ u64 ald8(const void* p) {
    return __hip_atomic_load((u64*)p, __ATOMIC_RELAXED, __HIP_MEMORY_SCOPE_AGENT);
}
__device__ __forceinline__ void ast8(void* p, u64 v) {
    __hip_atomic_store((u64*)p, v, __ATOMIC_RELAXED, __HIP_MEMORY_SCOPE_AGENT);
}
__device__ __forceinline__ void ast4u(void* p, unsigned v) {
    __hip_atomic_store((unsigned*)p, v, __ATOMIC_RELAXED, __HIP_MEMORY_SCOPE_AGENT);
}
union F2U { u64 q; float2 f; };
__device__ __forceinline__ float2 ald_f2(const float* p) { F2U u; u.q = ald8(p); return u.f; }
__device__ __forceinline__ void ast_f2(float* p, float x, float y) {
    F2U u; u.f.x = x; u.f.y = y; ast8(p, u.q);
}
__device__ __forceinline__ bf16x8 ald_bf8(const unsigned short* p) {
    union { u64 q[2]; bf16x8 v; } u;
    u.q[0] = ald8(p); u.q[1] = ald8(p + 4);
    return u.v;
}

struct Args {
    const int   *lin, *rin, *lch, *rch;
    const float *emb;
    const float *W_ioux, *b_ioux, *W_iouh, *b_iouh;
    const float *W_fx, *b_fx, *W_fh, *b_fh;
    const float *Wh, *bh, *Wp, *bp;
    unsigned short *WiouhT, *WfhT, *WxT, *Whb, *xcat, *hbf;
    float *cbuf, *ioub, *fpre, *out;
    unsigned *bars;        // [32] one-shot barrier counters; [31] = ready flag
};

// ---- fence-free one-shot grid barrier -------------------------------------
__device__ __forceinline__ void grid_bar(unsigned* bars, int idx, int nb)
{
    __syncthreads();   // emits s_waitcnt vmcnt(0): all sc-flagged stores at L3
    if (threadIdx.x == 0) {
        asm volatile("" ::: "memory");
        __hip_atomic_fetch_add(&bars[idx], 1u, __ATOMIC_RELAXED,
                               __HIP_MEMORY_SCOPE_AGENT);
        while (__hip_atomic_load(&bars[idx], __ATOMIC_RELAXED,
                                 __HIP_MEMORY_SCOPE_AGENT) < (unsigned)nb)
            __builtin_amdgcn_s_sleep(1);
        asm volatile("" ::: "memory");
    }
    __syncthreads();
}

// 32x32 fp32->bf16 transpose tile via LDS; packed 4B coherent stores
__device__ __forceinline__
void ttile(const float* __restrict__ src, int lds_, unsigned short* __restrict__ dst,
           int ldd, int k0, int n0, float (*ts)[33], int tid)
{
    const int tx = tid & 31, ty = tid >> 5;
#pragma unroll
    for (int i = 0; i < 4; ++i)
        ts[ty + 8 * i][tx] = src[(size_t)(k0 + ty + 8 * i) * lds_ + n0 + tx];
    __syncthreads();
    const int tx2 = tid & 15, ty2 = tid >> 4;   // 2 k-positions per thread
#pragma unroll
    for (int i = 0; i < 2; ++i) {
        const int row = n0 + ty2 + 16 * i;
        const unsigned lo = f2bf(ts[2 * tx2][ty2 + 16 * i]);
        const unsigned hi = f2bf(ts[2 * tx2 + 1][ty2 + 16 * i]);
        ast4u(&dst[(size_t)row * ldd + k0 + 2 * tx2], lo | (hi << 16));
    }
}

// -------- per-phase fused gather + dual GEMM (one block-task) --------------
__device__ __forceinline__
void gemm_task(int t, int lo, int B, int mti1, int nti1, int mti2, const Args& a)
{
    const int B2 = 2 * B;
    const int tid = threadIdx.x, w = tid >> 6, lane = tid & 63;
    const int m = lane & 15, q = lane >> 4;

    if (t < nti1) {
        // iou: [B2,512] (child-h sum, gathered on the fly) x [512,1536]
        const int mt = t % mti1, nb = t / mti1;
        const int colbase = nb * 256 + w * 64;
        const unsigned short* pA[2][4];
#pragma unroll
        for (int i = 0; i < 2; ++i) {
            const int r = mt * 32 + m + i * 16;
            int c[4] = {512, 512, 512, 512};
            int tree = 0;
            if (r < B2) {
                tree = (r >= B) ? 1 : 0;
                const int j = lo + r - tree * B;
                const int* ch = (tree ? a.rch : a.lch) + 4 * j;
                c[0] = ch[0]; c[1] = ch[1]; c[2] = ch[2]; c[3] = ch[3];
            }
            const unsigned short* hb = a.hbf + (size_t)tree * 513 * 512;
#pragma unroll
            for (int s = 0; s < 4; ++s) pA[i][s] = hb + (size_t)c[s] * 512;
        }
        f32x4 acc[2][4];
#pragma unroll
        for (int i = 0; i < 2; ++i)
#pragma unroll
            for (int j = 0; j < 4; ++j) acc[i][j] = (f32x4){0.f, 0.f, 0.f, 0.f};

        for (int k0 = 0; k0 < 512; k0 += 32) {
            const int koff = k0 + q * 8;
            bf16x8 af[2];
#pragma unroll
            for (int i = 0; i < 2; ++i) {
                float s[8] = {0.f, 0.f, 0.f, 0.f, 0.f, 0.f, 0.f, 0.f};
#pragma unroll
                for (int cc = 0; cc < 4; ++cc) {
                    bf16x8 v = ald_bf8(pA[i][cc] + koff);
#pragma unroll
                    for (int j = 0; j < 8; ++j) s[j] += (float)v[j];
                }
                bf16x8 av;
#pragma unroll
                for (int j = 0; j < 8; ++j) av[j] = (__bf16)s[j];
                af[i] = av;
            }
#pragma unroll
            for (int jj = 0; jj < 4; ++jj) {
                bf16x8 b = *(const bf16x8*)(a.WiouhT + (size_t)(colbase + jj * 16 + m) * 512 + koff);
                acc[0][jj] = mfma16(af[0], b, acc[0][jj]);
                acc[1][jj] = mfma16(af[1], b, acc[1][jj]);
            }
        }
#pragma unroll
        for (int i = 0; i < 2; ++i)
#pragma unroll
            for (int jj = 0; jj < 4; ++jj)
#pragma unroll
                for (int rr = 0; rr < 4; ++rr) {
                    const int R = mt * 32 + i * 16 + q * 4 + rr;
                    const int col = colbase + jj * 16 + m;
                    const int tr = (R >= B) ? 1 : 0;
                    const int jR = lo + R - tr * B;
                    float v = 0.f;
                    if (R < B2)
                        v = acc[i][jj][rr] + a.b_iouh[col]
                          + bf2f(a.xcat[(size_t)(tr * 512 + jR) * 2048 + col]);
                    const unsigned ov = __shfl_xor(__float_as_uint(v), 1, 64);
                    if (R < B2 && !(m & 1))
                        ast_f2(&a.ioub[(size_t)R * 1536 + col], v, __uint_as_float(ov));
                }
    } else {
        // f: [4*B2,512] (child h rows, direct) x [512,512]
        t -= nti1;
        const int mt = t % mti2, nb = t / mti2;
        const int colbase = nb * 256 + w * 64;
        const unsigned short* pA[2];
#pragma unroll
        for (int i = 0; i < 2; ++i) {
            const int rf = mt * 32 + m + i * 16;
            int tree = 0, c = 512;
            if (rf < 4 * B2) {
                const int r = rf >> 2, s = rf & 3;
                tree = (r >= B) ? 1 : 0;
                const int j = lo + r - tree * B;
                c = ((tree ? a.rch : a.lch) + 4 * j)[s];
            }
            pA[i] = a.hbf + ((size_t)tree * 513 + c) * 512;
        }
        f32x4 acc[2][4];
#pragma unroll
        for (int i = 0; i < 2; ++i)
#pragma unroll
            for (int j = 0; j < 4; ++j) acc[i][j] = (f32x4){0.f, 0.f, 0.f, 0.f};

        for (int k0 = 0; k0 < 512; k0 += 32) {
            const int koff = k0 + q * 8;
            bf16x8 a0 = ald_bf8(pA[0] + koff);
            bf16x8 a1 = ald_bf8(pA[1] + koff);
#pragma unroll
            for (int jj = 0; jj < 4; ++jj) {
                bf16x8 b = *(const bf16x8*)(a.WfhT + (size_t)(colbase + jj * 16 + m) * 512 + koff);
                acc[0][jj] = mfma16(a0, b, acc[0][jj]);
                acc[1][jj] = mfma16(a1, b, acc[1][jj]);
            }
        }
#pragma unroll
        for (int i = 0; i < 2; ++i)
#pragma unroll
            for (int jj = 0; jj < 4; ++jj)
#pragma unroll
                for (int rr = 0; rr < 4; ++rr) {
                    const int R = mt * 32 + i * 16 + q * 4 + rr;
                    const int col = colbase + jj * 16 + m;
                    const int rR = R >> 2;
                    const int tr = (rR >= B) ? 1 : 0;
                    const int jR = lo + rR - tr * B;
                    float v = 0.f;
                    if (R < 4 * B2)
                        v = acc[i][jj][rr] + a.b_fh[col]
                          + bf2f(a.xcat[(size_t)(tr * 512 + jR) * 2048 + 1536 + col]);
                    const unsigned ov = __shfl_xor(__float_as_uint(v), 1, 64);
                    if (R < 4 * B2 && !(m & 1))
                        ast_f2(&a.fpre[(size_t)R * 512 + col], v, __uint_as_float(ov));
                }
    }
}

// -------- general gating, 2 cols/thread (writes c fp32 8B, h bf16 4B) ------
__device__ __forceinline__
void gate_row(int r, int lo, int B, const Args& a)
{
    const int t2 = threadIdx.x * 2;
    const int tree = (r >= B) ? 1 : 0;
    const int j = lo + r - tree * B;
    const int* ch = (tree ? a.rch : a.lch) + 4 * j;
    const int c0 = ch[0], c1 = ch[1], c2 = ch[2], c3 = ch[3];
    float* cb = a.cbuf + (size_t)tree * 513 * 512;
    unsigned short* hb = a.hbf + (size_t)tree * 513 * 512;
    const float* ir = a.ioub + (size_t)r * 1536;
    const float* fr = a.fpre + (size_t)r * 4 * 512;

    const float2 igv = ald_f2(ir + t2);
    const float2 ogv = ald_f2(ir + 512 + t2);
    const float2 ugv = ald_f2(ir + 1024 + t2);
    const float2 f0 = ald_f2(fr + t2);
    const float2 f1 = ald_f2(fr + 512 + t2);
    const float2 f2v = ald_f2(fr + 1024 + t2);
    const float2 f3 = ald_f2(fr + 1536 + t2);
    const float2 cc0 = ald_f2(cb + (size_t)c0 * 512 + t2);
    const float2 cc1 = ald_f2(cb + (size_t)c1 * 512 + t2);
    const float2 cc2 = ald_f2(cb + (size_t)c2 * 512 + t2);
    const float2 cc3 = ald_f2(cb + (size_t)c3 * 512 + t2);

    const float cvx = sigm(igv.x) * tanhf(ugv.x)
        + sigm(f0.x) * cc0.x + sigm(f1.x) * cc1.x
        + sigm(f2v.x) * cc2.x + sigm(f3.x) * cc3.x;
    const float cvy = sigm(igv.y) * tanhf(ugv.y)
        + sigm(f0.y) * cc0.y + sigm(f1.y) * cc1.y
        + sigm(f2v.y) * cc2.y + sigm(f3.y) * cc3.y;
    ast_f2(cb + (size_t)j * 512 + t2, cvx, cvy);
    const unsigned hp = (unsigned)f2bf(sigm(ogv.x) * tanhf(cvx))
                      | ((unsigned)f2bf(sigm(ogv.y) * tanhf(cvy)) << 16);
    ast4u(hb + (size_t)j * 512 + t2, hp);
}

// ---------------------------- the mega-kernel ------------------------------
__global__ __launch_bounds__(256, 1)
void mega(Args a)
{
    const int tid = threadIdx.x, bid = blockIdx.x;
    const int G = gridDim.x;
    __shared__ float ts[32][33];

    // ---- barrier init: ws is poisoned 0xAA each call ----
    if (bid == 0 && tid == 0) {
        for (int i = 0; i < 31; ++i) ast4u(&a.bars[i], 0u);
        asm volatile("s_waitcnt vmcnt(0)" ::: "memory");
        ast4u(&a.bars[31], READY_MAGIC);
    }
    if (tid == 0) {
        while (__hip_atomic_load(&a.bars[31], __ATOMIC_RELAXED,
                                 __HIP_MEMORY_SCOPE_AGENT) != READY_MAGIC)
            __builtin_amdgcn_s_sleep(1);
        asm volatile("" ::: "memory");
    }
    __syncthreads();
    int bi = 0;   // barrier index (uniform across blocks)

    // ---- stage A: weight transpose/convert + zero pad rows (2305 tasks) ----
    for (int t = bid; t < 2305; t += G) {
        if (t < 768) {                       // W_iouh [512][1536] -> WiouhT
            ttile(a.W_iouh, 1536, a.WiouhT, 512, (t & 15) * 32, (t >> 4) * 32, ts, tid);
        } else if (t < 1024) {               // W_fh -> WfhT
            const int tt = t - 768;
            ttile(a.W_fh, 512, a.WfhT, 512, (tt & 15) * 32, (tt >> 4) * 32, ts, tid);
        } else if (t < 1792) {               // W_ioux -> WxT rows [0,1536)
            const int tt = t - 1024;
            ttile(a.W_ioux, 1536, a.WxT, 512, (tt & 15) * 32, (tt >> 4) * 32, ts, tid);
        } else if (t < 2048) {               // W_fx -> WxT rows [1536,2048)
            const int tt = t - 1792;
            ttile(a.W_fx, 512, a.WxT + (size_t)1536 * 512, 512, (tt & 15) * 32, (tt >> 4) * 32, ts, tid);
        } else if (t < 2304) {               // Wh -> bf16 copy (4B packed)
            unsigned* dst = (unsigned*)a.Whb;
            const size_t base = (size_t)(t - 2048) * 1024 + tid;
#pragma unroll
            for (int i = 0; i < 4; ++i) {
                const size_t idx = base + 256 * i;
                const unsigned lo = f2bf(a.Wh[2 * idx]);
                const unsigned hi = f2bf(a.Wh[2 * idx + 1]);
                ast4u(&dst[idx], lo | (hi << 16));
            }
        } else {                             // zero pad rows (child idx 512)
            u64* h0 = (u64*)(a.hbf + (size_t)512 * 512);
            u64* h1 = (u64*)(a.hbf + (size_t)1025 * 512);
            for (int i = tid; i < 128; i += 256) { ast8(&h0[i], 0ull); ast8(&h1[i], 0ull); }
            u64* c0p = (u64*)(a.cbuf + (size_t)512 * 512);
            u64* c1p = (u64*)(a.cbuf + (size_t)1025 * 512);
            for (int i = tid; i < 256; i += 256) { ast8(&c0p[i], 0ull); ast8(&c1p[i], 0ull); }
        }
        __syncthreads();                     // ts reusable next iteration
    }
    grid_bar(a.bars, bi++, G);

    // ---- stage B: xcat[1024][2048] = bf16(emb[tok]) @ WxT^T + bias ----
    for (int t = bid; t < 256; t += G) {
        const int mt = t & 31, nb = t >> 5;
        const int w = tid >> 6, lane = tid & 63;
        const int m = lane & 15, q = lane >> 4;
        const int colbase = nb * 256 + w * 64;
        const int r0 = mt * 32 + m, r1 = r0 + 16;
        const int tok0 = (r0 < 512) ? a.lin[r0] : a.rin[r0 - 512];
        const int tok1 = (r1 < 512) ? a.lin[r1] : a.rin[r1 - 512];
        const float* A0 = a.emb + (size_t)tok0 * 512;
        const float* A1 = a.emb + (size_t)tok1 * 512;

        f32x4 acc[2][4];
#pragma unroll
        for (int i = 0; i < 2; ++i)
#pragma unroll
            for (int j = 0; j < 4; ++j) acc[i][j] = (f32x4){0.f, 0.f, 0.f, 0.f};

        for (int k0 = 0; k0 < 512; k0 += 32) {
            const int koff = k0 + q * 8;
            bf16x8 a0 = load_f32_as_bf8(A0 + koff);
            bf16x8 a1 = load_f32_as_bf8(A1 + koff);
#pragma unroll
            for (int jj = 0; jj < 4; ++jj) {
                bf16x8 b = *(const bf16x8*)(a.WxT + (size_t)(colbase + jj * 16 + m) * 512 + koff);
                acc[0][jj] = mfma16(a0, b, acc[0][jj]);
                acc[1][jj] = mfma16(a1, b, acc[1][jj]);
            }
        }
#pragma unroll
        for (int i = 0; i < 2; ++i)
#pragma unroll
            for (int jj = 0; jj < 4; ++jj)
#pragma unroll
                for (int rr = 0; rr < 4; ++rr) {
                    const int R = mt * 32 + i * 16 + q * 4 + rr;
                    const int col = colbase + jj * 16 + m;
                    const float bias = (col < 1536) ? a.b_ioux[col] : a.b_fx[col - 1536];
                    const unsigned me = f2bf(acc[i][jj][rr] + bias);
                    const unsigned ov = __shfl_xor((int)me, 1, 64);
                    if (!(m & 1))
                        ast4u(&a.xcat[(size_t)R * 2048 + col], me | (ov << 16));
                }
    }
    grid_bar(a.bars, bi++, G);

    // ---- stage C0: leaf gating (children all pad-zero; GEMM acc == 0) ----
    {
        const int t2 = tid * 2;
        const float2 bi0 = *(const float2*)(a.b_iouh + t2);
        const float2 bi1 = *(const float2*)(a.b_iouh + 512 + t2);
        const float2 bi2 = *(const float2*)(a.b_iouh + 1024 + t2);
        for (int r = bid; r < 342; r += G) {
            const int tree = (r >= 171) ? 1 : 0;
            const int j = r - tree * 171;
            const unsigned short* xr = a.xcat + (size_t)(tree * 512 + j) * 2048;
            float* cb = a.cbuf + (size_t)tree * 513 * 512;
            unsigned short* hb = a.hbf + (size_t)tree * 513 * 512;
            const unsigned x0 = *(const unsigned*)(xr + t2);
            const unsigned x1 = *(const unsigned*)(xr + 512 + t2);
            const unsigned x2 = *(const unsigned*)(xr + 1024 + t2);
            const float cvx = sigm(bf2f((unsigned short)x0) + bi0.x)
                            * tanhf(bf2f((unsigned short)x2) + bi2.x);
            const float cvy = sigm(bf2f((unsigned short)(x0 >> 16)) + bi0.y)
                            * tanhf(bf2f((unsigned short)(x2 >> 16)) + bi2.y);
            const float ogx = sigm(bf2f((unsigned short)x1) + bi1.x);
            const float ogy = sigm(bf2f((unsigned short)(x1 >> 16)) + bi1.y);
            ast_f2(cb + (size_t)j * 512 + t2, cvx, cvy);
            const unsigned hp = (unsigned)f2bf(ogx * tanhf(cvx))
                              | ((unsigned)f2bf(ogy * tanhf(cvy)) << 16);
            ast4u(hb + (size_t)j * 512 + t2, hp);
        }
    }
    grid_bar(a.bars, bi++, G);

    // ---- phases d4..root: fused gather+GEMM, then gating ----
    static const int los[5] = {171, 427, 491, 507, 511};
    static const int Bs[5]  = {256, 64, 16, 4, 1};
    for (int ph = 0; ph < 5; ++ph) {
        const int lo = los[ph], B = Bs[ph], B2 = 2 * B;
        const int mti1 = (B2 + 31) >> 5, mti2 = (4 * B2 + 31) >> 5;
        const int nti1 = mti1 * 6;
        const int ntot = nti1 + mti2 * 2;
        for (int t = bid; t < ntot; t += G)
            gemm_task(t, lo, B, mti1, nti1, mti2, a);
        grid_bar(a.bars, bi++, G);
        if (ph < 4) {
            for (int r = bid; r < B2; r += G)
                gate_row(r, lo, B, a);
            grid_bar(a.bars, bi++, G);
        }
    }

    // ---- finale (block 0): root gating + similarity head, fully fused ----
    if (bid == 0) {
        __shared__ float sv[1024];
        const int t2 = tid * 2;
        // root cell states (og/h not needed: head consumes CELL states)
#pragma unroll
        for (int tree = 0; tree < 2; ++tree) {
            const int* ch = (tree ? a.rch : a.lch) + 4 * 511;
            const float* cb = a.cbuf + (size_t)tree * 513 * 512;
            const float* ir = a.ioub + (size_t)tree * 1536;
            const float* fr = a.fpre + (size_t)tree * 4 * 512;
            const float2 igv = ald_f2(ir + t2);
            const float2 ugv = ald_f2(ir + 1024 + t2);
            const float2 f0 = ald_f2(fr + t2);
            const float2 f1 = ald_f2(fr + 512 + t2);
            const float2 f2v = ald_f2(fr + 1024 + t2);
            const float2 f3 = ald_f2(fr + 1536 + t2);
            const float2 cc0 = ald_f2(cb + (size_t)ch[0] * 512 + t2);
            const float2 cc1 = ald_f2(cb + (size_t)ch[1] * 512 + t2);
            const float2 cc2 = ald_f2(cb + (size_t)ch[2] * 512 + t2);
            const float2 cc3 = ald_f2(cb + (size_t)ch[3] * 512 + t2);
            sv[tree * 512 + t2] = sigm(igv.x) * tanhf(ugv.x)
                + sigm(f0.x) * cc0.x + sigm(f1.x) * cc1.x
                + sigm(f2v.x) * cc2.x + sigm(f3.x) * cc3.x;
            sv[tree * 512 + t2 + 1] = sigm(igv.y) * tanhf(ugv.y)
                + sigm(f0.y) * cc0.y + sigm(f1.y) * cc1.y
                + sigm(f2v.y) * cc2.y + sigm(f3.y) * cc3.y;
        }
        __syncthreads();
        // vec = [lc*rc, |lc-rc|] in place
#pragma unroll
        for (int u = 0; u < 2; ++u) {
            const int k = tid + u * 256;
            if (k < 512) {
                const float lcv = sv[k], rcv = sv[512 + k];
                sv[k] = lcv * rcv;
                sv[512 + k] = fabsf(lcv - rcv);
            }
        }
        __syncthreads();
        // hid = sigmoid(vec @ Wh + bh); each thread owns cols 2t, 2t+1
        float a0 = 0.f, a1 = 0.f;
        for (int k = 0; k < 1024; ++k) {
            const unsigned int wv = *(const unsigned int*)(a.Whb + (size_t)k * 512 + t2);
            const float s = sv[k];
            a0 += s * bf2f((unsigned short)(wv & 0xffffu));
            a1 += s * bf2f((unsigned short)(wv >> 16));
        }
        const float h0 = sigm(a0 + a.bh[t2]);
        const float h1 = sigm(a1 + a.bh[t2 + 1]);
        float lp[5];
#pragma unroll
        for (int cc = 0; cc < 5; ++cc)
            lp[cc] = h0 * a.Wp[(size_t)t2 * 5 + cc]
                   + h1 * a.Wp[(size_t)(t2 + 1) * 5 + cc];
#pragma unroll
        for (int cc = 0; cc < 5; ++cc)
#pragma unroll
            for (int off = 32; off; off >>= 1)
                lp[cc] += __shfl_xor(lp[cc], off, 64);
        __shared__ float red[4][5];
        const int w = tid >> 6, lane = tid & 63;
        if (lane == 0)
#pragma unroll
            for (int cc = 0; cc < 5; ++cc) red[w][cc] = lp[cc];
        __syncthreads();
        if (tid == 0) {
            float lg[5], mx = -1e30f;
#pragma unroll
            for (int cc = 0; cc < 5; ++cc) {
                lg[cc] = red[0][cc] + red[1][cc] + red[2][cc] + red[3][cc] + a.bp[cc];
                mx = fmaxf(mx, lg[cc]);
            }
            float s = 0.f;
#pragma unroll
            for (int cc = 0; cc < 5; ++cc) s += __expf(lg[cc] - mx);
            const float lse = mx + __logf(s);
#pragma unroll
            for (int cc = 0; cc < 5; ++cc) a.out[cc] = lg[cc] - lse;
        }
    }
}

// ---------------- launch ----------------------------------------------------
extern "C" void kernel_launch(void* const* d_in, const int* in_sizes, int n_in,
                              void* d_out, int out_size, void* d_ws, size_t ws_size,
                              hipStream_t stream)
{
    (void)ws_size; (void)n_in; (void)in_sizes; (void)out_size;

    Args ha;
    ha.lin     = (const int*)d_in[0];
    ha.rin     = (const int*)d_in[1];
    ha.lch     = (const int*)d_in[2];
    ha.rch     = (const int*)d_in[3];
    ha.emb     = (const float*)d_in[4];
    ha.W_ioux  = (const float*)d_in[5];
    ha.b_ioux  = (const float*)d_in[6];
    ha.W_iouh  = (const float*)d_in[7];
    ha.b_iouh  = (const float*)d_in[8];
    ha.W_fx    = (const float*)d_in[9];
    ha.b_fx    = (const float*)d_in[10];
    ha.W_fh    = (const float*)d_in[11];
    ha.b_fh    = (const float*)d_in[12];
    ha.Wh      = (const float*)d_in[13];
    ha.bh      = (const float*)d_in[14];
    ha.Wp      = (const float*)d_in[15];
    ha.bp      = (const float*)d_in[16];
    ha.out     = (float*)d_out;

    char* p = (char*)d_ws;
    ha.WiouhT = (unsigned short*)p;  p += (size_t)1536 * 512 * 2;
    ha.WfhT   = (unsigned short*)p;  p += (size_t)512 * 512 * 2;
    ha.WxT    = (unsigned short*)p;  p += (size_t)2048 * 512 * 2;
    ha.Whb    = (unsigned short*)p;  p += (size_t)1024 * 512 * 2;
    ha.xcat   = (unsigned short*)p;  p += (size_t)1024 * 2048 * 2;
    ha.hbf    = (unsigned short*)p;  p += (size_t)2 * 513 * 512 * 2;
    ha.cbuf   = (float*)p;           p += (size_t)2 * 513 * 512 * 4;
    ha.ioub   = (float*)p;           p += (size_t)512 * 1536 * 4;
    ha.fpre   = (float*)p;           p += (size_t)2048 * 512 * 4;
    ha.bars   = (unsigned*)p;        p += (size_t)32 * 4;

    void* kargs[] = { &ha };
    hipLaunchCooperativeKernel((const void*)mega, dim3(GRID), dim3(256),
                               kargs, 0, stream);
}